// Round 9
// baseline (110.990 us; speedup 1.0000x reference)
//
#include <hip/hip_runtime.h>
#include <math.h>

#define H 256
#define HH 128
#define B_GRAPHS 512

typedef __attribute__((ext_vector_type(8))) short bfrag8;   // 8 bf16
typedef __attribute__((ext_vector_type(16))) float f32x16;

// ---------------- K0: pre-split W1 into 2 bf16 planes (truncate + residual),
// fragment-major: base = ((kks*2+g)*128 + col)*8 + e, k = kks*16 + g*8 + e ----------------
__global__ void k_prep_w1(const float* __restrict__ W1, ushort* __restrict__ W1b) {
  const int idx = blockIdx.x * 256 + threadIdx.x;  // 32768 = 256*128
  const int k = idx >> 7, c = idx & 127;
  const float v = W1[idx];  // W1 is [256][128] row-major
  const uint u = __builtin_bit_cast(uint, v);
  const float r = v - __builtin_bit_cast(float, u & 0xFFFF0000u);
  const int base = (((k >> 4) * 2 + ((k >> 3) & 1)) * 128 + c) * 8 + (k & 7);
  W1b[base] = (ushort)(u >> 16);
  W1b[32768 + base] = (ushort)(__builtin_bit_cast(uint, r) >> 16);
}

// ---------------- K1: segment bounds (batch is sorted) ----------------
__global__ void k_seg_bounds(const int* __restrict__ batch, int* __restrict__ seg_start,
                             int N, int B) {
  int b = blockIdx.x * blockDim.x + threadIdx.x;
  if (b > B) return;
  int lo = 0, hi = N;
  while (lo < hi) {
    int mid = (lo + hi) >> 1;
    if (batch[mid] < b) lo = mid + 1; else hi = mid;
  }
  seg_start[b] = lo;
}

// ---------------- K2: score MLP — split-K: block=32 nodes, wave w owns K-quarter ------
__device__ __forceinline__ void splitbf(const float4 v0, const float4 v1,
                                        bfrag8& a0, bfrag8& a1) {
  const float vals[8] = {v0.x, v0.y, v0.z, v0.w, v1.x, v1.y, v1.z, v1.w};
#pragma unroll
  for (int e = 0; e < 8; ++e) {
    const uint u = __builtin_bit_cast(uint, vals[e]);
    a0[e] = (short)(u >> 16);
    const float r = vals[e] - __builtin_bit_cast(float, u & 0xFFFF0000u);
    a1[e] = (short)(__builtin_bit_cast(uint, r) >> 16);
  }
}

__global__ __launch_bounds__(256, 3) void k_score_mfma(
    const float* __restrict__ x, const ushort* __restrict__ W1b,
    const float* __restrict__ b1, const float* __restrict__ W2,
    const float* __restrict__ b2, float* __restrict__ s_out) {
  __shared__ float part[4][16][128];  // 32 KB, reused across two epilogue phases
  const int t = threadIdx.x;
  const int lane = t & 63;
  const int w = t >> 6;          // wave id == K-quarter
  const int nl = lane & 31, g = lane >> 5;
  const int node0 = blockIdx.x * 32;

  f32x16 acc[4];
  acc[0] = (f32x16)0.f; acc[1] = (f32x16)0.f;
  acc[2] = (f32x16)0.f; acc[3] = (f32x16)0.f;

  // x loads: lane (nl,g) reads rows node0+nl, k = w*64 + sub*16 + g*8 (+0..7)
  const float* gsrc = x + (size_t)(node0 + nl) * H + w * 64 + g * 8;
  float4 xv[4][2];
#pragma unroll
  for (int sub = 0; sub < 4; ++sub) {
    xv[sub][0] = *(const float4*)(gsrc + sub * 16);
    xv[sub][1] = *(const float4*)(gsrc + sub * 16 + 4);
  }

#pragma unroll
  for (int sub = 0; sub < 4; ++sub) {
    const int kks = w * 4 + sub;
    bfrag8 a0, a1;
    splitbf(xv[sub][0], xv[sub][1], a0, a1);
#pragma unroll
    for (int j = 0; j < 4; ++j) {
      const ushort* bp = W1b + (size_t)((kks * 2 + g) * 128 + j * 32 + nl) * 8;
      const bfrag8 b0 = *(const bfrag8*)bp;
      const bfrag8 b1f = *(const bfrag8*)(bp + 32768);
      acc[j] = __builtin_amdgcn_mfma_f32_32x32x16_bf16(a0, b0, acc[j], 0, 0, 0);
      acc[j] = __builtin_amdgcn_mfma_f32_32x32x16_bf16(a0, b1f, acc[j], 0, 0, 0);
      acc[j] = __builtin_amdgcn_mfma_f32_32x32x16_bf16(a1, b0, acc[j], 0, 0, 0);
    }
  }

  // ---- epilogue: 2 phases; each phase combines 16 nodes x 128 hid across the 4 K-quarters
  const float b2v = b2[0];
  const int hb = (t & 15) * 8;   // 8 consecutive hidden cols per thread
  const int nloc = t >> 4;       // 0..15 node within phase
  float b1q[8], w2q[8];
#pragma unroll
  for (int e = 0; e < 8; ++e) {
    b1q[e] = b1[hb + e];
    w2q[e] = W2[hb + e];
  }

#pragma unroll
  for (int P = 0; P < 2; ++P) {
    // write this phase's partials: acc reg r = P*8 + rr -> node (rr&3)+8*(rr>>2)+4g
#pragma unroll
    for (int j = 0; j < 4; ++j)
#pragma unroll
      for (int rr = 0; rr < 8; ++rr) {
        const int nd = (rr & 3) + 8 * (rr >> 2) + 4 * g;
        part[w][nd][j * 32 + nl] = acc[j][P * 8 + rr];
      }
    __syncthreads();
    // combine: thread t sums 4 K-quarters for (nloc, hb..hb+8), layer-2, shfl-reduce
    float h8[8];
#pragma unroll
    for (int e = 0; e < 8; e += 4) {
      const float4 s0 = *(const float4*)&part[0][nloc][hb + e];
      const float4 s1 = *(const float4*)&part[1][nloc][hb + e];
      const float4 s2 = *(const float4*)&part[2][nloc][hb + e];
      const float4 s3 = *(const float4*)&part[3][nloc][hb + e];
      h8[e + 0] = s0.x + s1.x + s2.x + s3.x;
      h8[e + 1] = s0.y + s1.y + s2.y + s3.y;
      h8[e + 2] = s0.z + s1.z + s2.z + s3.z;
      h8[e + 3] = s0.w + s1.w + s2.w + s3.w;
    }
    float v = 0.f;
#pragma unroll
    for (int e = 0; e < 8; ++e)
      v = fmaf(fmaxf(h8[e] + b1q[e], 0.f), w2q[e], v);
#pragma unroll
    for (int m = 1; m < 16; m <<= 1) v += __shfl_xor(v, m);
    if ((t & 15) == 0) s_out[node0 + P * 16 + nloc] = v + b2v;
    if (P == 0) __syncthreads();
  }
}

// ---------------- K3: fused softmax stats + top-k select + single-pass pools ----------------
__global__ __launch_bounds__(512) void k_pool_fused(const float* __restrict__ x,
                                                    const float* __restrict__ s,
                                                    const int* __restrict__ seg_start,
                                                    float* __restrict__ pooled) {
  const int b = blockIdx.x;
  const int t = threadIdx.x;
  const int start = seg_start[b];
  const int end = seg_start[b + 1];
  const int n = end - start;

  __shared__ float s_lds[1024];
  __shared__ float red[512];
  __shared__ float thr_sh;
  __shared__ int thri_sh;
  __shared__ float r4[8][264];

  const bool fits = (n <= 1024);
  if (fits) {
    for (int i = t; i < n; i += 512) s_lds[i] = s[start + i];
  }
  __syncthreads();
  const float* sseg = fits ? s_lds : (s + start);

  float m = -INFINITY;
  for (int i = t; i < n; i += 512) m = fmaxf(m, sseg[i]);
  red[t] = m;
  __syncthreads();
  for (int off = 256; off > 0; off >>= 1) {
    if (t < off) red[t] = fmaxf(red[t], red[t + off]);
    __syncthreads();
  }
  const float smax = red[0];
  __syncthreads();
  float d = 0.f;
  for (int i = t; i < n; i += 512) d += __expf(sseg[i] - smax);
  red[t] = d;
  __syncthreads();
  for (int off = 256; off > 0; off >>= 1) {
    if (t < off) red[t] += red[t + off];
    __syncthreads();
  }
  const float denom = red[0];
  __syncthreads();
  const float inv_denom = (denom > 0.f) ? 1.f / denom : 0.f;

  int k = 0;
  if (n > 0) {
    k = (int)ceilf(0.05f * (float)n);
    if (k < 5) k = 5;
    if (k > 64) k = 64;
    if (k > n) k = n;
  }

  if (t < 64) {
    float pk = INFINITY;
    int pidx = -1;
    for (int r = 0; r < k; ++r) {
      float bk = -INFINITY;
      int bi = 0x7fffffff;
      for (int i = t; i < n; i += 64) {
        const float si = sseg[i];
        const int gi = start + i;
        const bool below = (si < pk) || (si == pk && gi > pidx);
        if (below && (si > bk || (si == bk && gi < bi))) { bk = si; bi = gi; }
      }
#pragma unroll
      for (int off = 32; off > 0; off >>= 1) {
        const float ok = __shfl_xor(bk, off);
        const int oi = __shfl_xor(bi, off);
        if (ok > bk || (ok == bk && oi < bi)) { bk = ok; bi = oi; }
      }
      pk = bk;
      pidx = bi;
    }
    if (t == 0) {
      thr_sh = (k > 0) ? pk : INFINITY;
      thri_sh = (k > 0) ? pidx : -1;
    }
  }
  __syncthreads();
  const float thr = thr_sh;
  const int thri = thri_sh;

  const int fq = t & 63;
  const int sub = t >> 6;
  float mean[4] = {0.f, 0.f, 0.f, 0.f};
  float attn[4] = {0.f, 0.f, 0.f, 0.f};
  float tk[4] = {0.f, 0.f, 0.f, 0.f};
  float mx[4] = {-INFINITY, -INFINITY, -INFINITY, -INFINITY};
  for (int i = sub; i < n; i += 8) {
    const float si = sseg[i];
    const float wi = __expf(si - smax);
    const int gi = start + i;
    const bool sel = (si > thr) || (si == thr && gi <= thri);
    const float4 xv = *reinterpret_cast<const float4*>(x + (size_t)gi * H + fq * 4);
    mean[0] += xv.x; mean[1] += xv.y; mean[2] += xv.z; mean[3] += xv.w;
    attn[0] = fmaf(xv.x, wi, attn[0]);
    attn[1] = fmaf(xv.y, wi, attn[1]);
    attn[2] = fmaf(xv.z, wi, attn[2]);
    attn[3] = fmaf(xv.w, wi, attn[3]);
    mx[0] = fmaxf(mx[0], xv.x);
    mx[1] = fmaxf(mx[1], xv.y);
    mx[2] = fmaxf(mx[2], xv.z);
    mx[3] = fmaxf(mx[3], xv.w);
    if (sel) {
      tk[0] += xv.x; tk[1] += xv.y; tk[2] += xv.z; tk[3] += xv.w;
    }
  }
  float* po = pooled + (size_t)b * 1024;
  const float invn = 1.f / (float)(n > 0 ? n : 1);
  const float invk = (k > 0) ? 1.f / (float)k : 0.f;
  *reinterpret_cast<float4*>(&r4[sub][fq * 4]) = make_float4(mean[0], mean[1], mean[2], mean[3]);
  __syncthreads();
  if (t < 256) {
    float tot = 0.f;
#pragma unroll
    for (int q = 0; q < 8; ++q) tot += r4[q][t];
    po[t] = tot * invn;
  }
  __syncthreads();
  *reinterpret_cast<float4*>(&r4[sub][fq * 4]) = make_float4(attn[0], attn[1], attn[2], attn[3]);
  __syncthreads();
  if (t < 256) {
    float tot = 0.f;
#pragma unroll
    for (int q = 0; q < 8; ++q) tot += r4[q][t];
    po[256 + t] = tot * inv_denom;
  }
  __syncthreads();
  *reinterpret_cast<float4*>(&r4[sub][fq * 4]) = make_float4(mx[0], mx[1], mx[2], mx[3]);
  __syncthreads();
  if (t < 256) {
    float tot = -INFINITY;
#pragma unroll
    for (int q = 0; q < 8; ++q) tot = fmaxf(tot, r4[q][t]);
    po[512 + t] = (n > 0) ? tot : 0.f;
  }
  __syncthreads();
  *reinterpret_cast<float4*>(&r4[sub][fq * 4]) = make_float4(tk[0], tk[1], tk[2], tk[3]);
  __syncthreads();
  if (t < 256) {
    float tot = 0.f;
#pragma unroll
    for (int q = 0; q < 8; ++q) tot += r4[q][t];
    po[768 + t] = tot * invk;
  }
}

// ---------------- K5: final GEMM [512,1024]@[1024,256], split-K=8 ----------------
__global__ __launch_bounds__(256) void k_gemm(const float* __restrict__ pooled,
                                              const float* __restrict__ Wf,
                                              float* __restrict__ gacc) {
  const int t = threadIdx.x;
  const int r0 = blockIdx.x * 8;
  const int kc0 = blockIdx.y * 128;
  __shared__ float ps[8][132];
  {
    const int r = t >> 5;
    const int c = (t & 31) << 2;
    *reinterpret_cast<float4*>(&ps[r][c]) =
        *reinterpret_cast<const float4*>(pooled + (size_t)(r0 + r) * 1024 + kc0 + c);
  }
  __syncthreads();
  float acc[8];
#pragma unroll
  for (int r = 0; r < 8; ++r) acc[r] = 0.f;
#pragma unroll 4
  for (int c = 0; c < 128; ++c) {
    const float wf = Wf[(size_t)(kc0 + c) * 256 + t];
#pragma unroll
    for (int r = 0; r < 8; ++r) acc[r] = fmaf(ps[r][c], wf, acc[r]);
  }
  float* go = gacc + ((size_t)blockIdx.y * B_GRAPHS + r0) * 256;
#pragma unroll
  for (int r = 0; r < 8; ++r) go[r * 256 + t] = acc[r];
}

// ---------------- K6: reduce split-K + bias + relu -> out ----------------
__global__ __launch_bounds__(256) void k_out(const float* __restrict__ gacc,
                                             const float* __restrict__ bf,
                                             float* __restrict__ out) {
  const int i = blockIdx.x * 256 + threadIdx.x;
  float v = bf[i & 255];
#pragma unroll
  for (int ks = 0; ks < 8; ++ks) v += gacc[(size_t)ks * (B_GRAPHS * 256) + i];
  out[i] = fmaxf(v, 0.f);
}

extern "C" void kernel_launch(void* const* d_in, const int* in_sizes, int n_in,
                              void* d_out, int out_size, void* d_ws, size_t ws_size,
                              hipStream_t stream) {
  const float* x  = (const float*)d_in[0];
  const int* batch = (const int*)d_in[1];
  const float* W1 = (const float*)d_in[2];
  const float* b1 = (const float*)d_in[3];
  const float* W2 = (const float*)d_in[4];
  const float* b2 = (const float*)d_in[5];
  const float* Wf = (const float*)d_in[6];
  const float* bf = (const float*)d_in[7];
  const int N = in_sizes[1];     // 131072
  const int B = B_GRAPHS;

  // ws floats: s[N] | seg_start[1024 ints] | pooled[B*1024] | gacc[8*B*256] | W1b[2*32768 u16]
  float* ws = (float*)d_ws;
  float* s = ws;
  int* seg_start = (int*)(ws + N);
  float* pooled = ws + N + 1024;
  float* gacc = pooled + (size_t)B * 1024;
  ushort* W1b = (ushort*)(gacc + (size_t)8 * B * 256);

  k_prep_w1<<<dim3(128), dim3(256), 0, stream>>>(W1, W1b);
  k_seg_bounds<<<dim3((B + 1 + 255) / 256), dim3(256), 0, stream>>>(batch, seg_start, N, B);
  k_score_mfma<<<dim3(N / 32), dim3(256), 0, stream>>>(x, W1b, b1, W2, b2, s);
  k_pool_fused<<<dim3(B), dim3(512), 0, stream>>>(x, s, seg_start, pooled);
  k_gemm<<<dim3(B / 8, 8), dim3(256), 0, stream>>>(pooled, Wf, gacc);
  k_out<<<dim3((B * 256) / 256), dim3(256), 0, stream>>>(gacc, bf, (float*)d_out);
}

// Round 10
// 107.994 us; speedup vs baseline: 1.0277x; 1.0277x over previous
//
#include <hip/hip_runtime.h>
#include <math.h>

#define H 256
#define HH 128
#define B_GRAPHS 512

typedef __attribute__((ext_vector_type(8))) short bfrag8;   // 8 bf16
typedef __attribute__((ext_vector_type(16))) float f32x16;

// ---------------- K0: pre-split W1 into 2 bf16 planes (truncate + residual),
// fragment-major: base = ((kks*2+g)*128 + col)*8 + e, k = kks*16 + g*8 + e ----------------
__global__ void k_prep_w1(const float* __restrict__ W1, ushort* __restrict__ W1b) {
  const int idx = blockIdx.x * 256 + threadIdx.x;  // 32768 = 256*128
  const int k = idx >> 7, c = idx & 127;
  const float v = W1[idx];  // W1 is [256][128] row-major
  const uint u = __builtin_bit_cast(uint, v);
  const float r = v - __builtin_bit_cast(float, u & 0xFFFF0000u);
  const int base = (((k >> 4) * 2 + ((k >> 3) & 1)) * 128 + c) * 8 + (k & 7);
  W1b[base] = (ushort)(u >> 16);
  W1b[32768 + base] = (ushort)(__builtin_bit_cast(uint, r) >> 16);
}

// ---------------- K1: segment bounds (batch is sorted) ----------------
__global__ void k_seg_bounds(const int* __restrict__ batch, int* __restrict__ seg_start,
                             int N, int B) {
  int b = blockIdx.x * blockDim.x + threadIdx.x;
  if (b > B) return;
  int lo = 0, hi = N;
  while (lo < hi) {
    int mid = (lo + hi) >> 1;
    if (batch[mid] < b) lo = mid + 1; else hi = mid;
  }
  seg_start[b] = lo;
}

// ---------------- K2: score MLP — whole W1 resident in LDS, barrier-free main loop ------
__device__ __forceinline__ void splitbf(const float4 v0, const float4 v1,
                                        bfrag8& a0, bfrag8& a1) {
  const float vals[8] = {v0.x, v0.y, v0.z, v0.w, v1.x, v1.y, v1.z, v1.w};
#pragma unroll
  for (int e = 0; e < 8; ++e) {
    const uint u = __builtin_bit_cast(uint, vals[e]);
    a0[e] = (short)(u >> 16);
    const float r = vals[e] - __builtin_bit_cast(float, u & 0xFFFF0000u);
    a1[e] = (short)(__builtin_bit_cast(uint, r) >> 16);
  }
}

__global__ __launch_bounds__(1024, 4) void k_score_mfma(
    const float* __restrict__ x, const ushort* __restrict__ W1b,
    const float* __restrict__ b1, const float* __restrict__ W2,
    const float* __restrict__ b2, float* __restrict__ s_out) {
  extern __shared__ ushort bsh[];  // 131072 B: plane0 [32768], plane1 [32768]
  const int t = threadIdx.x;
  const int lane = t & 63;
  const int w = t >> 6;          // 0..15
  const int nl = lane & 31, g = lane >> 5;

  // ---- stage full W1b into LDS (once), coalesced: 128 B per thread ----
  {
    const uint4* src = (const uint4*)W1b + t * 8;
    uint4* dst = (uint4*)bsh + t * 8;
#pragma unroll
    for (int i = 0; i < 8; ++i) dst[i] = src[i];
  }
  __syncthreads();

  const int chunk = blockIdx.x * 16 + w;   // 256 blocks * 16 waves = 4096 chunks
  const int node0 = chunk * 32;
  const float* gsrc = x + (size_t)(node0 + nl) * H + g * 8;

  f32x16 acc[4];
  acc[0] = (f32x16)0.f; acc[1] = (f32x16)0.f;
  acc[2] = (f32x16)0.f; acc[3] = (f32x16)0.f;

  // rolling 2-substep batches of A loads (32 B/lane/substep, full-line coalesced)
  float4 xa[2][2], xb[2][2];
#pragma unroll
  for (int q = 0; q < 2; ++q) {
    xa[q][0] = *(const float4*)(gsrc + q * 16);
    xa[q][1] = *(const float4*)(gsrc + q * 16 + 4);
  }

#pragma unroll
  for (int pair = 0; pair < 8; ++pair) {
    if (pair < 7) {
#pragma unroll
      for (int q = 0; q < 2; ++q) {
        xb[q][0] = *(const float4*)(gsrc + ((pair + 1) * 2 + q) * 16);
        xb[q][1] = *(const float4*)(gsrc + ((pair + 1) * 2 + q) * 16 + 4);
      }
    }
#pragma unroll
    for (int q = 0; q < 2; ++q) {
      const int kks = pair * 2 + q;
      bfrag8 a0, a1;
      splitbf(xa[q][0], xa[q][1], a0, a1);
#pragma unroll
      for (int j = 0; j < 4; ++j) {
        const ushort* bp = &bsh[(size_t)((kks * 2 + g) * 128 + j * 32 + nl) * 8];
        const bfrag8 b0 = *(const bfrag8*)bp;
        const bfrag8 b1f = *(const bfrag8*)(bp + 32768);
        acc[j] = __builtin_amdgcn_mfma_f32_32x32x16_bf16(a0, b0, acc[j], 0, 0, 0);
        acc[j] = __builtin_amdgcn_mfma_f32_32x32x16_bf16(a0, b1f, acc[j], 0, 0, 0);
        acc[j] = __builtin_amdgcn_mfma_f32_32x32x16_bf16(a1, b0, acc[j], 0, 0, 0);
      }
    }
    if (pair < 7) {
#pragma unroll
      for (int q = 0; q < 2; ++q) {
        xa[q][0] = xb[q][0];
        xa[q][1] = xb[q][1];
      }
    }
  }

  // ---- epilogue: layer 2 + cross-lane reduce (proven C/D map: row=(r&3)+8*(r>>2)+4g) ----
  float b1v[4], w2v[4];
#pragma unroll
  for (int j = 0; j < 4; ++j) {
    b1v[j] = b1[j * 32 + nl];
    w2v[j] = W2[j * 32 + nl];
  }
  float p[16];
#pragma unroll
  for (int r = 0; r < 16; ++r) {
    float v = 0.f;
#pragma unroll
    for (int j = 0; j < 4; ++j)
      v = fmaf(fmaxf(acc[j][r] + b1v[j], 0.f), w2v[j], v);
#pragma unroll
    for (int m = 1; m <= 16; m <<= 1) v += __shfl_xor(v, m);
    p[r] = v;
  }
  if (nl == 0) {
    const float bb = b2[0];
#pragma unroll
    for (int r = 0; r < 16; ++r) {
      const int row = (r & 3) + 8 * (r >> 2) + 4 * g;
      s_out[node0 + row] = p[r] + bb;
    }
  }
}

// ---------------- K3: fused softmax stats + top-k select + single-pass pools ----------------
__global__ __launch_bounds__(512) void k_pool_fused(const float* __restrict__ x,
                                                    const float* __restrict__ s,
                                                    const int* __restrict__ seg_start,
                                                    float* __restrict__ pooled) {
  const int b = blockIdx.x;
  const int t = threadIdx.x;
  const int start = seg_start[b];
  const int end = seg_start[b + 1];
  const int n = end - start;

  __shared__ float s_lds[1024];
  __shared__ float red[512];
  __shared__ float thr_sh;
  __shared__ int thri_sh;
  __shared__ float r4[8][264];

  const bool fits = (n <= 1024);
  if (fits) {
    for (int i = t; i < n; i += 512) s_lds[i] = s[start + i];
  }
  __syncthreads();
  const float* sseg = fits ? s_lds : (s + start);

  float m = -INFINITY;
  for (int i = t; i < n; i += 512) m = fmaxf(m, sseg[i]);
  red[t] = m;
  __syncthreads();
  for (int off = 256; off > 0; off >>= 1) {
    if (t < off) red[t] = fmaxf(red[t], red[t + off]);
    __syncthreads();
  }
  const float smax = red[0];
  __syncthreads();
  float d = 0.f;
  for (int i = t; i < n; i += 512) d += __expf(sseg[i] - smax);
  red[t] = d;
  __syncthreads();
  for (int off = 256; off > 0; off >>= 1) {
    if (t < off) red[t] += red[t + off];
    __syncthreads();
  }
  const float denom = red[0];
  __syncthreads();
  const float inv_denom = (denom > 0.f) ? 1.f / denom : 0.f;

  int k = 0;
  if (n > 0) {
    k = (int)ceilf(0.05f * (float)n);
    if (k < 5) k = 5;
    if (k > 64) k = 64;
    if (k > n) k = n;
  }

  if (t < 64) {
    float pk = INFINITY;
    int pidx = -1;
    for (int r = 0; r < k; ++r) {
      float bk = -INFINITY;
      int bi = 0x7fffffff;
      for (int i = t; i < n; i += 64) {
        const float si = sseg[i];
        const int gi = start + i;
        const bool below = (si < pk) || (si == pk && gi > pidx);
        if (below && (si > bk || (si == bk && gi < bi))) { bk = si; bi = gi; }
      }
#pragma unroll
      for (int off = 32; off > 0; off >>= 1) {
        const float ok = __shfl_xor(bk, off);
        const int oi = __shfl_xor(bi, off);
        if (ok > bk || (ok == bk && oi < bi)) { bk = ok; bi = oi; }
      }
      pk = bk;
      pidx = bi;
    }
    if (t == 0) {
      thr_sh = (k > 0) ? pk : INFINITY;
      thri_sh = (k > 0) ? pidx : -1;
    }
  }
  __syncthreads();
  const float thr = thr_sh;
  const int thri = thri_sh;

  const int fq = t & 63;
  const int sub = t >> 6;
  float mean[4] = {0.f, 0.f, 0.f, 0.f};
  float attn[4] = {0.f, 0.f, 0.f, 0.f};
  float tk[4] = {0.f, 0.f, 0.f, 0.f};
  float mx[4] = {-INFINITY, -INFINITY, -INFINITY, -INFINITY};
  for (int i = sub; i < n; i += 8) {
    const float si = sseg[i];
    const float wi = __expf(si - smax);
    const int gi = start + i;
    const bool sel = (si > thr) || (si == thr && gi <= thri);
    const float4 xv = *reinterpret_cast<const float4*>(x + (size_t)gi * H + fq * 4);
    mean[0] += xv.x; mean[1] += xv.y; mean[2] += xv.z; mean[3] += xv.w;
    attn[0] = fmaf(xv.x, wi, attn[0]);
    attn[1] = fmaf(xv.y, wi, attn[1]);
    attn[2] = fmaf(xv.z, wi, attn[2]);
    attn[3] = fmaf(xv.w, wi, attn[3]);
    mx[0] = fmaxf(mx[0], xv.x);
    mx[1] = fmaxf(mx[1], xv.y);
    mx[2] = fmaxf(mx[2], xv.z);
    mx[3] = fmaxf(mx[3], xv.w);
    if (sel) {
      tk[0] += xv.x; tk[1] += xv.y; tk[2] += xv.z; tk[3] += xv.w;
    }
  }
  float* po = pooled + (size_t)b * 1024;
  const float invn = 1.f / (float)(n > 0 ? n : 1);
  const float invk = (k > 0) ? 1.f / (float)k : 0.f;
  *reinterpret_cast<float4*>(&r4[sub][fq * 4]) = make_float4(mean[0], mean[1], mean[2], mean[3]);
  __syncthreads();
  if (t < 256) {
    float tot = 0.f;
#pragma unroll
    for (int q = 0; q < 8; ++q) tot += r4[q][t];
    po[t] = tot * invn;
  }
  __syncthreads();
  *reinterpret_cast<float4*>(&r4[sub][fq * 4]) = make_float4(attn[0], attn[1], attn[2], attn[3]);
  __syncthreads();
  if (t < 256) {
    float tot = 0.f;
#pragma unroll
    for (int q = 0; q < 8; ++q) tot += r4[q][t];
    po[256 + t] = tot * inv_denom;
  }
  __syncthreads();
  *reinterpret_cast<float4*>(&r4[sub][fq * 4]) = make_float4(mx[0], mx[1], mx[2], mx[3]);
  __syncthreads();
  if (t < 256) {
    float tot = -INFINITY;
#pragma unroll
    for (int q = 0; q < 8; ++q) tot = fmaxf(tot, r4[q][t]);
    po[512 + t] = (n > 0) ? tot : 0.f;
  }
  __syncthreads();
  *reinterpret_cast<float4*>(&r4[sub][fq * 4]) = make_float4(tk[0], tk[1], tk[2], tk[3]);
  __syncthreads();
  if (t < 256) {
    float tot = 0.f;
#pragma unroll
    for (int q = 0; q < 8; ++q) tot += r4[q][t];
    po[768 + t] = tot * invk;
  }
}

// ---------------- K5: final GEMM [512,1024]@[1024,256], split-K=8 ----------------
__global__ __launch_bounds__(256) void k_gemm(const float* __restrict__ pooled,
                                              const float* __restrict__ Wf,
                                              float* __restrict__ gacc) {
  const int t = threadIdx.x;
  const int r0 = blockIdx.x * 8;
  const int kc0 = blockIdx.y * 128;
  __shared__ float ps[8][132];
  {
    const int r = t >> 5;
    const int c = (t & 31) << 2;
    *reinterpret_cast<float4*>(&ps[r][c]) =
        *reinterpret_cast<const float4*>(pooled + (size_t)(r0 + r) * 1024 + kc0 + c);
  }
  __syncthreads();
  float acc[8];
#pragma unroll
  for (int r = 0; r < 8; ++r) acc[r] = 0.f;
#pragma unroll 4
  for (int c = 0; c < 128; ++c) {
    const float wf = Wf[(size_t)(kc0 + c) * 256 + t];
#pragma unroll
    for (int r = 0; r < 8; ++r) acc[r] = fmaf(ps[r][c], wf, acc[r]);
  }
  float* go = gacc + ((size_t)blockIdx.y * B_GRAPHS + r0) * 256;
#pragma unroll
  for (int r = 0; r < 8; ++r) go[r * 256 + t] = acc[r];
}

// ---------------- K6: reduce split-K + bias + relu -> out ----------------
__global__ __launch_bounds__(256) void k_out(const float* __restrict__ gacc,
                                             const float* __restrict__ bf,
                                             float* __restrict__ out) {
  const int i = blockIdx.x * 256 + threadIdx.x;
  float v = bf[i & 255];
#pragma unroll
  for (int ks = 0; ks < 8; ++ks) v += gacc[(size_t)ks * (B_GRAPHS * 256) + i];
  out[i] = fmaxf(v, 0.f);
}

extern "C" void kernel_launch(void* const* d_in, const int* in_sizes, int n_in,
                              void* d_out, int out_size, void* d_ws, size_t ws_size,
                              hipStream_t stream) {
  const float* x  = (const float*)d_in[0];
  const int* batch = (const int*)d_in[1];
  const float* W1 = (const float*)d_in[2];
  const float* b1 = (const float*)d_in[3];
  const float* W2 = (const float*)d_in[4];
  const float* b2 = (const float*)d_in[5];
  const float* Wf = (const float*)d_in[6];
  const float* bf = (const float*)d_in[7];
  const int N = in_sizes[1];     // 131072
  const int B = B_GRAPHS;

  // ws floats: s[N] | seg_start[1024 ints] | pooled[B*1024] | gacc[8*B*256] | W1b[2*32768 u16]
  float* ws = (float*)d_ws;
  float* s = ws;
  int* seg_start = (int*)(ws + N);
  float* pooled = ws + N + 1024;
  float* gacc = pooled + (size_t)B * 1024;
  ushort* W1b = (ushort*)(gacc + (size_t)8 * B * 256);

  static bool attr_set = false;
  if (!attr_set) {
    hipFuncSetAttribute((const void*)k_score_mfma,
                        hipFuncAttributeMaxDynamicSharedMemorySize, 131072);
    attr_set = true;
  }

  k_prep_w1<<<dim3(128), dim3(256), 0, stream>>>(W1, W1b);
  k_seg_bounds<<<dim3((B + 1 + 255) / 256), dim3(256), 0, stream>>>(batch, seg_start, N, B);
  k_score_mfma<<<dim3(N / 512), dim3(1024), 131072, stream>>>(x, W1b, b1, W2, b2, s);
  k_pool_fused<<<dim3(B), dim3(512), 0, stream>>>(x, s, seg_start, pooled);
  k_gemm<<<dim3(B / 8, 8), dim3(256), 0, stream>>>(pooled, Wf, gacc);
  k_out<<<dim3((B * 256) / 256), dim3(256), 0, stream>>>(gacc, bf, (float*)d_out);
}